// Round 18
// baseline (472.330 us; speedup 1.0000x reference)
//
#include <hip/hip_runtime.h>
#include <math.h>

#define NN 100000
#define NE 3200000
#define FIN 128
#define HID 64
#define NC 7
#define BW 512                    // bucket width (nodes)
#define NBUC 196                  // ceil(NN/BW)
#define CAP 20480                 // per-bucket capacity (mean 16327, sigma~128)
#define CHUNK 8192                // edges staged per block in pass A (dense runs)
#define NCHUNK ((NE + CHUNK - 1) / CHUNK)   // 391
#define PROJB ((NN + 127) / 128)            // 782 proj1 blocks

typedef __attribute__((ext_vector_type(8))) short bhalf8;   // 8 bf16 = 4 VGPR
typedef __attribute__((ext_vector_type(4))) float f32x4;    // MFMA acc

__device__ __forceinline__ unsigned int f2bf(float x) {
    unsigned int u = __float_as_uint(x);
    return (u + 0x7fffu + ((u >> 16) & 1u)) >> 16;   // RTNE
}
__device__ __forceinline__ float bf_lo(unsigned int u) {
    return __uint_as_float(u << 16);
}
__device__ __forceinline__ float bf_hi(unsigned int u) {
    return __uint_as_float(u & 0xffff0000u);
}
// swizzled 16B-window index within a 256B LDS row (8-window spread)
__device__ __forceinline__ int swz(int row, int win) {
    return (win & 8) | ((win ^ row) & 7);
}

// ---- init: bucket cursors + W -> bf16 wb[ch][k] ---------------------------
__global__ __launch_bounds__(256) void k_init(int* __restrict__ gcur,
                                              const float* __restrict__ W1l,
                                              const float* __restrict__ W1r,
                                              unsigned short* __restrict__ wb) {
    int b = blockIdx.x, t = threadIdx.x;
    if (b == 0) {
        if (t < NBUC) gcur[t] = t * CAP;
    } else {
#pragma unroll
        for (int e = 0; e < 4; ++e) {
            int idx = (b - 1) * 1024 + e * 256 + t;
            float v = (idx < 8192) ? W1l[idx] : W1r[idx - 8192];
            wb[idx] = (unsigned short)f2bf(v);
        }
    }
}

// shared-memory union: passA staging vs proj1 x-tile
union SmemU {
    unsigned short xls[128 * 128];          // 32 KB bf16 x-tile (swizzled)
    struct {
        unsigned int pay[CHUNK];            // 32 KB
        int h[NBUC];
        int lcur[NBUC];
        unsigned char buc[CHUNK];           // 8 KB
    } a;
};

// ---- fused: blocks 0..NCHUNK-1 = passA; rest = MFMA proj1 ----
__global__ __launch_bounds__(256) void k_pa_proj(const int* __restrict__ src,
                                                 const int* __restrict__ dst,
                                                 int* __restrict__ gcur,
                                                 unsigned int* __restrict__ ebuf,
                                                 const float* __restrict__ x,
                                                 const unsigned short* __restrict__ wb,
                                                 unsigned int* __restrict__ p1b,
                                                 float* __restrict__ r1) {
    __shared__ SmemU smem;
    int t = threadIdx.x;
    if (blockIdx.x < NCHUNK) {
        // ---------------- passA ----------------
        for (int i = t; i < NBUC; i += 256) smem.a.h[i] = 0;
        __syncthreads();
        int base = blockIdx.x * CHUNK;
        int cnt = min(CHUNK, NE - base);
        for (int i = t; i < cnt; i += 256) {
            int s = src[base + i];
            int d = dst[base + i];
            int b = d >> 9;
            smem.a.pay[i] = ((unsigned)(d & 511) << 17) | (unsigned)s;
            smem.a.buc[i] = (unsigned char)b;
            atomicAdd(&smem.a.h[b], 1);
        }
        __syncthreads();
        for (int i = t; i < NBUC; i += 256)
            smem.a.lcur[i] = smem.a.h[i] ? atomicAdd(&gcur[i], smem.a.h[i]) : 0;
        __syncthreads();
        for (int i = t; i < cnt; i += 256) {
            int p = atomicAdd(&smem.a.lcur[smem.a.buc[i]], 1);
            ebuf[p] = smem.a.pay[i];
        }
    } else {
        // ---------------- proj1: MFMA bf16 ----------------
        int n0 = (blockIdx.x - NCHUNK) * 128;
        // stage x-tile -> bf16 LDS, swizzled windows
#pragma unroll
        for (int u = 0; u < 8; ++u) {
            int fid = u * 256 + t;
            int row = fid >> 4;      // 0..127
            int win = fid & 15;      // 16B window (8 bf16)
            int n = n0 + row;
            uint4 w = make_uint4(0u, 0u, 0u, 0u);
            if (n < NN) {
                const float4* xp = (const float4*)&x[(size_t)n * 128 + win * 8];
                float4 v0 = xp[0], v1 = xp[1];
                w.x = f2bf(v0.x) | (f2bf(v0.y) << 16);
                w.y = f2bf(v0.z) | (f2bf(v0.w) << 16);
                w.z = f2bf(v1.x) | (f2bf(v1.y) << 16);
                w.w = f2bf(v1.z) | (f2bf(v1.w) << 16);
            }
            *(uint4*)((char*)smem.xls + row * 256 + swz(row, win) * 16) = w;
        }
        __syncthreads();
        int wv = t >> 6;          // wave 0..3 -> row-tiles {2wv, 2wv+1}
        int l = t & 63;
        int lr = l & 15;          // A-row / B-col / C-col within tile
        int lg = l >> 4;          // k-group
        f32x4 acc[2][8];
#pragma unroll
        for (int rt = 0; rt < 2; ++rt)
#pragma unroll
            for (int ct = 0; ct < 8; ++ct) acc[rt][ct] = (f32x4)0.f;
        bhalf8 afr[2], bfr[8];
        for (int ks = 0; ks < 4; ++ks) {
#pragma unroll
            for (int rt = 0; rt < 2; ++rt) {
                int row = (wv * 2 + rt) * 16 + lr;
                int win = ks * 4 + lg;
                afr[rt] = *(bhalf8*)((char*)smem.xls + row * 256 + swz(row, win) * 16);
            }
#pragma unroll
            for (int ct = 0; ct < 8; ++ct)
                bfr[ct] = *(const bhalf8*)&wb[(ct * 16 + lr) * 128 + ks * 32 + lg * 8];
#pragma unroll
            for (int ct = 0; ct < 8; ++ct) {
                acc[0][ct] = __builtin_amdgcn_mfma_f32_16x16x32_bf16(
                    afr[0], bfr[ct], acc[0][ct], 0, 0, 0);
                acc[1][ct] = __builtin_amdgcn_mfma_f32_16x16x32_bf16(
                    afr[1], bfr[ct], acc[1][ct], 0, 0, 0);
            }
        }
        // C write: row = lg*4+j, col = lr
        unsigned short* p1h = (unsigned short*)p1b;
#pragma unroll
        for (int rt = 0; rt < 2; ++rt) {
#pragma unroll
            for (int j = 0; j < 4; ++j) {
                int n = n0 + (wv * 2 + rt) * 16 + lg * 4 + j;
                if (n < NN) {
#pragma unroll
                    for (int ct = 0; ct < 8; ++ct) {
                        float vv = acc[rt][ct][j];
                        int ch = ct * 16 + lr;
                        if (ct < 4)
                            p1h[(size_t)n * 64 + ch] = (unsigned short)f2bf(vv);
                        else
                            r1[(size_t)n * 64 + (ch - 64)] = vv;
                    }
                }
            }
        }
    }
}

// ---- pass B: per bucket -> per-node counts/offsets (coalesced), skey ------
__global__ __launch_bounds__(512) void k_passB(const unsigned int* __restrict__ ebuf,
                                               const int* __restrict__ gcur,
                                               int* __restrict__ offs,
                                               int* __restrict__ cnti,
                                               int* __restrict__ skey) {
    __shared__ int lcnt[BW];
    __shared__ int lcur[BW];
    __shared__ int s2[256];
    int b = blockIdx.x, t = threadIdx.x;
    int beg = b * CAP, end = gcur[b];
    lcnt[t] = 0;
    __syncthreads();
    for (int i = beg + t; i < end; i += 512)
        atomicAdd(&lcnt[ebuf[i] >> 17], 1);
    __syncthreads();
    int c0 = 0, c1 = 0;
    if (t < 256) {
        c0 = lcnt[2 * t];
        c1 = lcnt[2 * t + 1];
        s2[t] = c0 + c1;
    }
    __syncthreads();
    for (int d = 1; d < 256; d <<= 1) {
        int a = 0;
        if (t < 256 && t >= d) a = s2[t - d];
        __syncthreads();
        if (t < 256) s2[t] += a;
        __syncthreads();
    }
    if (t < 256) {
        int excl = s2[t] - (c0 + c1);
        int o0 = beg + excl;
        int o1 = o0 + c0;
        lcur[2 * t] = o0;
        lcur[2 * t + 1] = o1;
        int n0 = b * BW + 2 * t;
        if (n0 < NN)     { offs[n0] = o0;     cnti[n0] = c0; }
        if (n0 + 1 < NN) { offs[n0 + 1] = o1; cnti[n0 + 1] = c1; }
    }
    __syncthreads();
    for (int i = beg + t; i < end; i += 512) {
        unsigned v = ebuf[i];
        int p = atomicAdd(&lcur[v >> 17], 1);
        skey[p] = (int)(v & 0x1FFFFu);
    }
}

// ---- agg1g: channel-group x XCD-affine gather; h (f32) in place over r1 ---
// group g = blockIdx & 7 -> uints g*4..g*4+3 (channels g*8..g*8+7).
// Each XCD's blocks touch only their group's 1.6 MB p1b slice -> L2-resident.
// Wave per (node, group): 64 lanes = 16 edges x 4 uints; 2-deep unroll.
__global__ __launch_bounds__(256) void k_agg1g(const unsigned int* __restrict__ p1b,
                                               float* __restrict__ r1,
                                               const int* __restrict__ skey,
                                               const int* __restrict__ offs,
                                               const int* __restrict__ cnti,
                                               const float* __restrict__ b1) {
    int gidx = blockIdx.x;
    int g = gidx & 7;                       // channel group
    int n = (gidx >> 3) * 4 + (threadIdx.x >> 6);
    int l = threadIdx.x & 63;
    if (n >= NN) return;
    int e16 = l >> 2;                       // edge sub 0..15
    int q = (l & 3) + g * 4;                // uint index within p1 row
    int off = offs[n];
    int dc = cnti[n];
    float a0 = 0.f, a1 = 0.f;
    int e = e16;
    for (; e + 16 < dc; e += 32) {          // 2 edges in flight per lane
        int s0 = skey[off + e];
        int s1 = skey[off + e + 16];
        unsigned v0 = p1b[(size_t)s0 * 32 + q];
        unsigned v1 = p1b[(size_t)s1 * 32 + q];
        a0 += bf_lo(v0); a1 += bf_hi(v0);
        a0 += bf_lo(v1); a1 += bf_hi(v1);
    }
    for (; e < dc; e += 16) {
        int s0 = skey[off + e];
        unsigned v0 = p1b[(size_t)s0 * 32 + q];
        a0 += bf_lo(v0); a1 += bf_hi(v0);
    }
    // reduce across the 16 edge-subs (lanes with same q)
#pragma unroll
    for (int d = 4; d < 64; d <<= 1) {
        a0 += __shfl_xor(a0, d);
        a1 += __shfl_xor(a1, d);
    }
    // lanes 0..7 write channels g*8 + 0..7 (lane q'=l>>1 holds uint q')
    float va = __shfl(a0, l >> 1);
    float vb = __shfl(a1, l >> 1);
    if (l < 8) {
        int ch = g * 8 + l;
        float acc = (l & 1) ? vb : va;
        float inv = (dc > 0) ? 1.f / (float)dc : 0.f;
        float h = fmaxf(acc * inv + r1[(size_t)n * 64 + ch] + b1[ch], 0.f);
        r1[(size_t)n * 64 + ch] = h;        // disjoint slice per group: no race
    }
}

// ---- proj2: dense, thread per node; p2 stride 8 (32B-aligned rows) --------
__global__ __launch_bounds__(256) void k_proj2(const float* __restrict__ h,
                                               const float* __restrict__ W2l,
                                               const float* __restrict__ W2r,
                                               float* __restrict__ p2,
                                               float* __restrict__ r2) {
    __shared__ float swl[NC][64];
    __shared__ float swr[NC][64];
    int t = threadIdx.x;
    for (int i = t; i < NC * 64; i += 256) {
        swl[i >> 6][i & 63] = W2l[i];
        swr[i >> 6][i & 63] = W2r[i];
    }
    __syncthreads();
    int n = blockIdx.x * 256 + t;
    if (n >= NN) return;
    float al[NC], ar[NC];
#pragma unroll
    for (int c = 0; c < NC; ++c) { al[c] = 0.f; ar[c] = 0.f; }
    const float4* H = (const float4*)(h + (size_t)n * 64);
#pragma unroll
    for (int q = 0; q < 16; ++q) {
        float4 u = H[q];
        int k = q * 4;
#pragma unroll
        for (int c = 0; c < NC; ++c) {
            al[c] += u.x * swl[c][k] + u.y * swl[c][k + 1] +
                     u.z * swl[c][k + 2] + u.w * swl[c][k + 3];
            ar[c] += u.x * swr[c][k] + u.y * swr[c][k + 1] +
                     u.z * swr[c][k + 2] + u.w * swr[c][k + 3];
        }
    }
#pragma unroll
    for (int c = 0; c < NC; ++c) {
        p2[(size_t)n * 8 + c] = al[c];      // stride 8
        r2[(size_t)n * NC + c] = ar[c];
    }
}

// ---- agg2 + bias + log_softmax fused: 8 lanes per node; 8-deep gather ILP -
__global__ __launch_bounds__(256) void k_agg2f(const float* __restrict__ p2,
                                               const float* __restrict__ r2,
                                               const int* __restrict__ skey,
                                               const int* __restrict__ offs,
                                               const int* __restrict__ cnti,
                                               const float* __restrict__ b2,
                                               float* __restrict__ out) {
    int tid = blockIdx.x * 256 + threadIdx.x;
    int n = tid >> 3;
    int c = tid & 7;
    if (n >= NN) return;
    bool act = (c < NC);
    int off = offs[n];
    int dc = cnti[n];
    int i = off, end = off + dc;
    float acc = 0.f;
    for (; i + 7 < end; i += 8) {
        int s0 = skey[i],     s1 = skey[i + 1], s2 = skey[i + 2], s3 = skey[i + 3];
        int s4 = skey[i + 4], s5 = skey[i + 5], s6 = skey[i + 6], s7 = skey[i + 7];
        if (act) {
            float x0 = p2[(size_t)s0 * 8 + c];
            float x1 = p2[(size_t)s1 * 8 + c];
            float x2 = p2[(size_t)s2 * 8 + c];
            float x3 = p2[(size_t)s3 * 8 + c];
            float x4 = p2[(size_t)s4 * 8 + c];
            float x5 = p2[(size_t)s5 * 8 + c];
            float x6 = p2[(size_t)s6 * 8 + c];
            float x7 = p2[(size_t)s7 * 8 + c];
            acc += x0 + x1 + x2 + x3 + x4 + x5 + x6 + x7;
        }
    }
    for (; i + 3 < end; i += 4) {
        int s0 = skey[i], s1 = skey[i + 1], s2 = skey[i + 2], s3 = skey[i + 3];
        if (act) {
            acc += p2[(size_t)s0 * 8 + c];
            acc += p2[(size_t)s1 * 8 + c];
            acc += p2[(size_t)s2 * 8 + c];
            acc += p2[(size_t)s3 * 8 + c];
        }
    }
    for (; i < end; ++i) if (act) acc += p2[(size_t)skey[i] * 8 + c];
    float inv = (dc > 0) ? 1.f / (float)dc : 0.f;
    float v = act ? (acc * inv + r2[(size_t)n * NC + c] + b2[c]) : -INFINITY;
    float m = v;
#pragma unroll
    for (int d = 1; d < 8; d <<= 1) m = fmaxf(m, __shfl_xor(m, d));
    float ev = act ? expf(v - m) : 0.f;
    float s = ev;
#pragma unroll
    for (int d = 1; d < 8; d <<= 1) s += __shfl_xor(s, d);
    if (act) out[(size_t)n * NC + c] = v - m - logf(s);
}

extern "C" void kernel_launch(void* const* d_in, const int* in_sizes, int n_in,
                              void* d_out, int out_size, void* d_ws, size_t ws_size,
                              hipStream_t stream) {
    const float* x   = (const float*)d_in[0];
    const int*   ei  = (const int*)d_in[1];   // [2, NE] int32
    const float* W1l = (const float*)d_in[2];
    const float* W1r = (const float*)d_in[3];
    const float* b1  = (const float*)d_in[4];
    const float* W2l = (const float*)d_in[5];
    const float* W2r = (const float*)d_in[6];
    const float* b2  = (const float*)d_in[7];
    float* out = (float*)d_out;

    const int* src = ei;
    const int* dst = ei + NE;

    // workspace layout (4-byte units), ~78 MB total
    int* gcur  = (int*)d_ws;                // 256
    int* cnti  = gcur + 256;                // NN
    int* offs  = cnti + NN;                 // NN
    unsigned int* ebuf = (unsigned int*)(offs + NN);        // NBUC*CAP
    int* skey  = (int*)(ebuf + (size_t)NBUC * CAP);         // NBUC*CAP
    unsigned short* wb = (unsigned short*)(skey + (size_t)NBUC * CAP); // 16384 bf16
    unsigned int* p1b = (unsigned int*)((int*)wb + 8192);   // NN*32
    float* r1  = (float*)(p1b + (size_t)NN * 32);           // NN*64; becomes h
    float* p2  = r1 + (size_t)NN * HID;     // NN*8 (stride 8)
    float* r2  = p2 + (size_t)NN * 8;       // NN*7

    k_init   <<<17, 256, 0, stream>>>(gcur, W1l, W1r, wb);
    k_pa_proj<<<NCHUNK + PROJB, 256, 0, stream>>>(src, dst, gcur, ebuf,
                                                  x, wb, p1b, r1);
    k_passB  <<<NBUC, 512, 0, stream>>>(ebuf, gcur, offs, cnti, skey);
    k_agg1g  <<<8 * ((NN + 3) / 4), 256, 0, stream>>>(p1b, r1, skey, offs,
                                                      cnti, b1);
    k_proj2  <<<(NN + 255) / 256, 256, 0, stream>>>(r1, W2l, W2r, p2, r2);
    k_agg2f  <<<(NN * 8 + 255) / 256, 256, 0, stream>>>(p2, r2, skey, offs,
                                                        cnti, b2, out);
}

// Round 19
// 345.948 us; speedup vs baseline: 1.3653x; 1.3653x over previous
//
#include <hip/hip_runtime.h>
#include <math.h>

#define NN 100000
#define NE 3200000
#define FIN 128
#define HID 64
#define NC 7
#define BW 512                    // bucket width (nodes)
#define NBUC 196                  // ceil(NN/BW)
#define CAP 20480                 // per-bucket capacity (mean 16327, sigma~128)
#define CHUNK 8192                // edges staged per block in pass A (dense runs)
#define NCHUNK ((NE + CHUNK - 1) / CHUNK)   // 391
#define PROJB ((NN + 127) / 128)            // 782 proj1 blocks

typedef __attribute__((ext_vector_type(8))) short bhalf8;   // 8 bf16 = 4 VGPR
typedef __attribute__((ext_vector_type(4))) float f32x4;    // MFMA acc

__device__ __forceinline__ unsigned int f2bf(float x) {
    unsigned int u = __float_as_uint(x);
    return (u + 0x7fffu + ((u >> 16) & 1u)) >> 16;   // RTNE
}
__device__ __forceinline__ float bf_lo(unsigned int u) {
    return __uint_as_float(u << 16);
}
__device__ __forceinline__ float bf_hi(unsigned int u) {
    return __uint_as_float(u & 0xffff0000u);
}
// swizzled 16B-window index within a 256B LDS row (8-window spread)
__device__ __forceinline__ int swz(int row, int win) {
    return (win & 8) | ((win ^ row) & 7);
}

// ---- init: bucket cursors + W -> bf16 wb[ch][k] ---------------------------
__global__ __launch_bounds__(256) void k_init(int* __restrict__ gcur,
                                              const float* __restrict__ W1l,
                                              const float* __restrict__ W1r,
                                              unsigned short* __restrict__ wb) {
    int b = blockIdx.x, t = threadIdx.x;
    if (b == 0) {
        if (t < NBUC) gcur[t] = t * CAP;
    } else {
#pragma unroll
        for (int e = 0; e < 4; ++e) {
            int idx = (b - 1) * 1024 + e * 256 + t;
            float v = (idx < 8192) ? W1l[idx] : W1r[idx - 8192];
            wb[idx] = (unsigned short)f2bf(v);
        }
    }
}

// shared-memory union: passA staging vs proj1 x-tile
union SmemU {
    unsigned short xls[128 * 128];          // 32 KB bf16 x-tile (swizzled)
    struct {
        unsigned int pay[CHUNK];            // 32 KB
        int h[NBUC];
        int lcur[NBUC];
        unsigned char buc[CHUNK];           // 8 KB
    } a;
};

// ---- fused: blocks 0..NCHUNK-1 = passA; rest = MFMA proj1 ----
// p1 is stored GROUP-MAJOR: p1h[g][n][8 shorts], g = ch>>3 (8 slices x 1.6MB)
__global__ __launch_bounds__(256) void k_pa_proj(const int* __restrict__ src,
                                                 const int* __restrict__ dst,
                                                 int* __restrict__ gcur,
                                                 unsigned int* __restrict__ ebuf,
                                                 const float* __restrict__ x,
                                                 const unsigned short* __restrict__ wb,
                                                 unsigned int* __restrict__ p1b,
                                                 float* __restrict__ r1) {
    __shared__ SmemU smem;
    int t = threadIdx.x;
    if (blockIdx.x < NCHUNK) {
        // ---------------- passA ----------------
        for (int i = t; i < NBUC; i += 256) smem.a.h[i] = 0;
        __syncthreads();
        int base = blockIdx.x * CHUNK;
        int cnt = min(CHUNK, NE - base);
        for (int i = t; i < cnt; i += 256) {
            int s = src[base + i];
            int d = dst[base + i];
            int b = d >> 9;
            smem.a.pay[i] = ((unsigned)(d & 511) << 17) | (unsigned)s;
            smem.a.buc[i] = (unsigned char)b;
            atomicAdd(&smem.a.h[b], 1);
        }
        __syncthreads();
        for (int i = t; i < NBUC; i += 256)
            smem.a.lcur[i] = smem.a.h[i] ? atomicAdd(&gcur[i], smem.a.h[i]) : 0;
        __syncthreads();
        for (int i = t; i < cnt; i += 256) {
            int p = atomicAdd(&smem.a.lcur[smem.a.buc[i]], 1);
            ebuf[p] = smem.a.pay[i];
        }
    } else {
        // ---------------- proj1: MFMA bf16 ----------------
        int n0 = (blockIdx.x - NCHUNK) * 128;
        // stage x-tile -> bf16 LDS, swizzled windows
#pragma unroll
        for (int u = 0; u < 8; ++u) {
            int fid = u * 256 + t;
            int row = fid >> 4;      // 0..127
            int win = fid & 15;      // 16B window (8 bf16)
            int n = n0 + row;
            uint4 w = make_uint4(0u, 0u, 0u, 0u);
            if (n < NN) {
                const float4* xp = (const float4*)&x[(size_t)n * 128 + win * 8];
                float4 v0 = xp[0], v1 = xp[1];
                w.x = f2bf(v0.x) | (f2bf(v0.y) << 16);
                w.y = f2bf(v0.z) | (f2bf(v0.w) << 16);
                w.z = f2bf(v1.x) | (f2bf(v1.y) << 16);
                w.w = f2bf(v1.z) | (f2bf(v1.w) << 16);
            }
            *(uint4*)((char*)smem.xls + row * 256 + swz(row, win) * 16) = w;
        }
        __syncthreads();
        int wv = t >> 6;          // wave 0..3 -> row-tiles {2wv, 2wv+1}
        int l = t & 63;
        int lr = l & 15;          // A-row / B-col / C-col within tile
        int lg = l >> 4;          // k-group
        f32x4 acc[2][8];
#pragma unroll
        for (int rt = 0; rt < 2; ++rt)
#pragma unroll
            for (int ct = 0; ct < 8; ++ct) acc[rt][ct] = (f32x4)0.f;
        bhalf8 afr[2], bfr[8];
        for (int ks = 0; ks < 4; ++ks) {
#pragma unroll
            for (int rt = 0; rt < 2; ++rt) {
                int row = (wv * 2 + rt) * 16 + lr;
                int win = ks * 4 + lg;
                afr[rt] = *(bhalf8*)((char*)smem.xls + row * 256 + swz(row, win) * 16);
            }
#pragma unroll
            for (int ct = 0; ct < 8; ++ct)
                bfr[ct] = *(const bhalf8*)&wb[(ct * 16 + lr) * 128 + ks * 32 + lg * 8];
#pragma unroll
            for (int ct = 0; ct < 8; ++ct) {
                acc[0][ct] = __builtin_amdgcn_mfma_f32_16x16x32_bf16(
                    afr[0], bfr[ct], acc[0][ct], 0, 0, 0);
                acc[1][ct] = __builtin_amdgcn_mfma_f32_16x16x32_bf16(
                    afr[1], bfr[ct], acc[1][ct], 0, 0, 0);
            }
        }
        // C write: row = lg*4+j, col = lr ; p1 group-major
        unsigned short* p1h = (unsigned short*)p1b;
#pragma unroll
        for (int rt = 0; rt < 2; ++rt) {
#pragma unroll
            for (int j = 0; j < 4; ++j) {
                int n = n0 + (wv * 2 + rt) * 16 + lg * 4 + j;
                if (n < NN) {
#pragma unroll
                    for (int ct = 0; ct < 8; ++ct) {
                        float vv = acc[rt][ct][j];
                        int ch = ct * 16 + lr;
                        if (ct < 4) {
                            int g = ch >> 3;
                            p1h[(size_t)g * NN * 8 + (size_t)n * 8 + (ch & 7)] =
                                (unsigned short)f2bf(vv);
                        } else {
                            r1[(size_t)n * 64 + (ch - 64)] = vv;
                        }
                    }
                }
            }
        }
    }
}

// ---- pass B: per bucket -> per-node counts/offsets (coalesced), skey ------
__global__ __launch_bounds__(512) void k_passB(const unsigned int* __restrict__ ebuf,
                                               const int* __restrict__ gcur,
                                               int* __restrict__ offs,
                                               int* __restrict__ cnti,
                                               int* __restrict__ skey) {
    __shared__ int lcnt[BW];
    __shared__ int lcur[BW];
    __shared__ int s2[256];
    int b = blockIdx.x, t = threadIdx.x;
    int beg = b * CAP, end = gcur[b];
    lcnt[t] = 0;
    __syncthreads();
    for (int i = beg + t; i < end; i += 512)
        atomicAdd(&lcnt[ebuf[i] >> 17], 1);
    __syncthreads();
    int c0 = 0, c1 = 0;
    if (t < 256) {
        c0 = lcnt[2 * t];
        c1 = lcnt[2 * t + 1];
        s2[t] = c0 + c1;
    }
    __syncthreads();
    for (int d = 1; d < 256; d <<= 1) {
        int a = 0;
        if (t < 256 && t >= d) a = s2[t - d];
        __syncthreads();
        if (t < 256) s2[t] += a;
        __syncthreads();
    }
    if (t < 256) {
        int excl = s2[t] - (c0 + c1);
        int o0 = beg + excl;
        int o1 = o0 + c0;
        lcur[2 * t] = o0;
        lcur[2 * t + 1] = o1;
        int n0 = b * BW + 2 * t;
        if (n0 < NN)     { offs[n0] = o0;     cnti[n0] = c0; }
        if (n0 + 1 < NN) { offs[n0 + 1] = o1; cnti[n0 + 1] = c1; }
    }
    __syncthreads();
    for (int i = beg + t; i < end; i += 512) {
        unsigned v = ebuf[i];
        int p = atomicAdd(&lcur[v >> 17], 1);
        skey[p] = (int)(v & 0x1FFFFu);
    }
}

// ---- agg1g: channel-group x XCD-affine gather over GROUP-MAJOR p1 --------
// group g = blockIdx & 7 -> contiguous slice p1b + g*NN*4 uints (1.6 MB).
// Round-robin block->XCD => each XCD's random gathers stay in its L2 slice.
// Wave per (node, group): 16 edges x 4 lanes (16B granule); 2-deep unroll.
__global__ __launch_bounds__(256) void k_agg1g(const unsigned int* __restrict__ p1b,
                                               float* __restrict__ r1,
                                               const int* __restrict__ skey,
                                               const int* __restrict__ offs,
                                               const int* __restrict__ cnti,
                                               const float* __restrict__ b1) {
    int gidx = blockIdx.x;
    int g = gidx & 7;                       // channel group (XCD-affine)
    int n = (gidx >> 3) * 4 + (threadIdx.x >> 6);
    int l = threadIdx.x & 63;
    if (n >= NN) return;
    int e16 = l >> 2;                       // edge sub 0..15
    int ql = l & 3;                         // uint within the 16B granule
    const unsigned int* slice = p1b + (size_t)g * NN * 4;
    int off = offs[n];
    int dc = cnti[n];
    float a0 = 0.f, a1 = 0.f;
    int e = e16;
    for (; e + 16 < dc; e += 32) {          // 2 edges in flight per lane
        int s0 = skey[off + e];
        int s1 = skey[off + e + 16];
        unsigned v0 = slice[(size_t)s0 * 4 + ql];
        unsigned v1 = slice[(size_t)s1 * 4 + ql];
        a0 += bf_lo(v0); a1 += bf_hi(v0);
        a0 += bf_lo(v1); a1 += bf_hi(v1);
    }
    for (; e < dc; e += 16) {
        int s0 = skey[off + e];
        unsigned v0 = slice[(size_t)s0 * 4 + ql];
        a0 += bf_lo(v0); a1 += bf_hi(v0);
    }
    // reduce across the 16 edge-subs (lanes with same ql)
#pragma unroll
    for (int d = 4; d < 64; d <<= 1) {
        a0 += __shfl_xor(a0, d);
        a1 += __shfl_xor(a1, d);
    }
    // lanes 0..7 write channels g*8 + 0..7 (lane l>>1 holds uint l>>1)
    float va = __shfl(a0, l >> 1);
    float vb = __shfl(a1, l >> 1);
    if (l < 8) {
        int ch = g * 8 + l;
        float acc = (l & 1) ? vb : va;
        float inv = (dc > 0) ? 1.f / (float)dc : 0.f;
        float h = fmaxf(acc * inv + r1[(size_t)n * 64 + ch] + b1[ch], 0.f);
        r1[(size_t)n * 64 + ch] = h;        // disjoint slice per group: no race
    }
}

// ---- proj2: dense, thread per node; p2 stride 8 (32B-aligned rows) --------
__global__ __launch_bounds__(256) void k_proj2(const float* __restrict__ h,
                                               const float* __restrict__ W2l,
                                               const float* __restrict__ W2r,
                                               float* __restrict__ p2,
                                               float* __restrict__ r2) {
    __shared__ float swl[NC][64];
    __shared__ float swr[NC][64];
    int t = threadIdx.x;
    for (int i = t; i < NC * 64; i += 256) {
        swl[i >> 6][i & 63] = W2l[i];
        swr[i >> 6][i & 63] = W2r[i];
    }
    __syncthreads();
    int n = blockIdx.x * 256 + t;
    if (n >= NN) return;
    float al[NC], ar[NC];
#pragma unroll
    for (int c = 0; c < NC; ++c) { al[c] = 0.f; ar[c] = 0.f; }
    const float4* H = (const float4*)(h + (size_t)n * 64);
#pragma unroll
    for (int q = 0; q < 16; ++q) {
        float4 u = H[q];
        int k = q * 4;
#pragma unroll
        for (int c = 0; c < NC; ++c) {
            al[c] += u.x * swl[c][k] + u.y * swl[c][k + 1] +
                     u.z * swl[c][k + 2] + u.w * swl[c][k + 3];
            ar[c] += u.x * swr[c][k] + u.y * swr[c][k + 1] +
                     u.z * swr[c][k + 2] + u.w * swr[c][k + 3];
        }
    }
#pragma unroll
    for (int c = 0; c < NC; ++c) {
        p2[(size_t)n * 8 + c] = al[c];      // stride 8
        r2[(size_t)n * NC + c] = ar[c];
    }
}

// ---- agg2 + bias + log_softmax fused: 8 lanes per node; 8-deep gather ILP -
__global__ __launch_bounds__(256) void k_agg2f(const float* __restrict__ p2,
                                               const float* __restrict__ r2,
                                               const int* __restrict__ skey,
                                               const int* __restrict__ offs,
                                               const int* __restrict__ cnti,
                                               const float* __restrict__ b2,
                                               float* __restrict__ out) {
    int tid = blockIdx.x * 256 + threadIdx.x;
    int n = tid >> 3;
    int c = tid & 7;
    if (n >= NN) return;
    bool act = (c < NC);
    int off = offs[n];
    int dc = cnti[n];
    int i = off, end = off + dc;
    float acc = 0.f;
    for (; i + 7 < end; i += 8) {
        int s0 = skey[i],     s1 = skey[i + 1], s2 = skey[i + 2], s3 = skey[i + 3];
        int s4 = skey[i + 4], s5 = skey[i + 5], s6 = skey[i + 6], s7 = skey[i + 7];
        if (act) {
            float x0 = p2[(size_t)s0 * 8 + c];
            float x1 = p2[(size_t)s1 * 8 + c];
            float x2 = p2[(size_t)s2 * 8 + c];
            float x3 = p2[(size_t)s3 * 8 + c];
            float x4 = p2[(size_t)s4 * 8 + c];
            float x5 = p2[(size_t)s5 * 8 + c];
            float x6 = p2[(size_t)s6 * 8 + c];
            float x7 = p2[(size_t)s7 * 8 + c];
            acc += x0 + x1 + x2 + x3 + x4 + x5 + x6 + x7;
        }
    }
    for (; i + 3 < end; i += 4) {
        int s0 = skey[i], s1 = skey[i + 1], s2 = skey[i + 2], s3 = skey[i + 3];
        if (act) {
            acc += p2[(size_t)s0 * 8 + c];
            acc += p2[(size_t)s1 * 8 + c];
            acc += p2[(size_t)s2 * 8 + c];
            acc += p2[(size_t)s3 * 8 + c];
        }
    }
    for (; i < end; ++i) if (act) acc += p2[(size_t)skey[i] * 8 + c];
    float inv = (dc > 0) ? 1.f / (float)dc : 0.f;
    float v = act ? (acc * inv + r2[(size_t)n * NC + c] + b2[c]) : -INFINITY;
    float m = v;
#pragma unroll
    for (int d = 1; d < 8; d <<= 1) m = fmaxf(m, __shfl_xor(m, d));
    float ev = act ? expf(v - m) : 0.f;
    float s = ev;
#pragma unroll
    for (int d = 1; d < 8; d <<= 1) s += __shfl_xor(s, d);
    if (act) out[(size_t)n * NC + c] = v - m - logf(s);
}

extern "C" void kernel_launch(void* const* d_in, const int* in_sizes, int n_in,
                              void* d_out, int out_size, void* d_ws, size_t ws_size,
                              hipStream_t stream) {
    const float* x   = (const float*)d_in[0];
    const int*   ei  = (const int*)d_in[1];   // [2, NE] int32
    const float* W1l = (const float*)d_in[2];
    const float* W1r = (const float*)d_in[3];
    const float* b1  = (const float*)d_in[4];
    const float* W2l = (const float*)d_in[5];
    const float* W2r = (const float*)d_in[6];
    const float* b2  = (const float*)d_in[7];
    float* out = (float*)d_out;

    const int* src = ei;
    const int* dst = ei + NE;

    // workspace layout (4-byte units), ~78 MB total
    int* gcur  = (int*)d_ws;                // 256
    int* cnti  = gcur + 256;                // NN
    int* offs  = cnti + NN;                 // NN
    unsigned int* ebuf = (unsigned int*)(offs + NN);        // NBUC*CAP
    int* skey  = (int*)(ebuf + (size_t)NBUC * CAP);         // NBUC*CAP
    unsigned short* wb = (unsigned short*)(skey + (size_t)NBUC * CAP); // 16384 bf16
    unsigned int* p1b = (unsigned int*)((int*)wb + 8192);   // NN*32 (group-major)
    float* r1  = (float*)(p1b + (size_t)NN * 32);           // NN*64; becomes h
    float* p2  = r1 + (size_t)NN * HID;     // NN*8 (stride 8)
    float* r2  = p2 + (size_t)NN * 8;       // NN*7

    k_init   <<<17, 256, 0, stream>>>(gcur, W1l, W1r, wb);
    k_pa_proj<<<NCHUNK + PROJB, 256, 0, stream>>>(src, dst, gcur, ebuf,
                                                  x, wb, p1b, r1);
    k_passB  <<<NBUC, 512, 0, stream>>>(ebuf, gcur, offs, cnti, skey);
    k_agg1g  <<<8 * ((NN + 3) / 4), 256, 0, stream>>>(p1b, r1, skey, offs,
                                                      cnti, b1);
    k_proj2  <<<(NN + 255) / 256, 256, 0, stream>>>(r1, W2l, W2r, p2, r2);
    k_agg2f  <<<(NN * 8 + 255) / 256, 256, 0, stream>>>(p2, r2, skey, offs,
                                                        cnti, b2, out);
}

// Round 20
// 180.854 us; speedup vs baseline: 2.6117x; 1.9129x over previous
//
#include <hip/hip_runtime.h>
#include <math.h>

#define NN 100000
#define NE 3200000
#define FIN 128
#define HID 64
#define NC 7
#define BW 512                    // bucket width (nodes)
#define NBUC 196                  // ceil(NN/BW)
#define CAP 20480                 // per-bucket capacity (mean 16327, sigma~128)
#define CHUNK 8192                // edges staged per block in pass A (dense runs)
#define NCHUNK ((NE + CHUNK - 1) / CHUNK)   // 391
#define PROJB ((NN + 127) / 128)            // 782 proj1 blocks

typedef __attribute__((ext_vector_type(8))) short bhalf8;   // 8 bf16 = 4 VGPR
typedef __attribute__((ext_vector_type(4))) float f32x4;    // MFMA acc

__device__ __forceinline__ unsigned int f2bf(float x) {
    unsigned int u = __float_as_uint(x);
    return (u + 0x7fffu + ((u >> 16) & 1u)) >> 16;   // RTNE
}
__device__ __forceinline__ float bf_lo(unsigned int u) {
    return __uint_as_float(u << 16);
}
__device__ __forceinline__ float bf_hi(unsigned int u) {
    return __uint_as_float(u & 0xffff0000u);
}
// swizzled 16B-window index within a 256B LDS row (8-window spread)
__device__ __forceinline__ int swz(int row, int win) {
    return (win & 8) | ((win ^ row) & 7);
}

// ---- init: bucket cursors + W -> bf16 wb[ch][k] ---------------------------
__global__ __launch_bounds__(256) void k_init(int* __restrict__ gcur,
                                              const float* __restrict__ W1l,
                                              const float* __restrict__ W1r,
                                              unsigned short* __restrict__ wb) {
    int b = blockIdx.x, t = threadIdx.x;
    if (b == 0) {
        if (t < NBUC) gcur[t] = t * CAP;
    } else {
#pragma unroll
        for (int e = 0; e < 4; ++e) {
            int idx = (b - 1) * 1024 + e * 256 + t;
            float v = (idx < 8192) ? W1l[idx] : W1r[idx - 8192];
            wb[idx] = (unsigned short)f2bf(v);
        }
    }
}

// shared-memory union: passA staging vs proj1 x-tile
union SmemU {
    unsigned short xls[128 * 128];          // 32 KB bf16 x-tile (swizzled)
    struct {
        unsigned int pay[CHUNK];            // 32 KB
        int h[NBUC];
        int lcur[NBUC];
        unsigned char buc[CHUNK];           // 8 KB
    } a;
};

// ---- fused: blocks 0..NCHUNK-1 = passA; rest = MFMA proj1 ----
__global__ __launch_bounds__(256) void k_pa_proj(const int* __restrict__ src,
                                                 const int* __restrict__ dst,
                                                 int* __restrict__ gcur,
                                                 unsigned int* __restrict__ ebuf,
                                                 const float* __restrict__ x,
                                                 const unsigned short* __restrict__ wb,
                                                 unsigned int* __restrict__ p1b,
                                                 float* __restrict__ r1) {
    __shared__ SmemU smem;
    int t = threadIdx.x;
    if (blockIdx.x < NCHUNK) {
        // ---------------- passA ----------------
        for (int i = t; i < NBUC; i += 256) smem.a.h[i] = 0;
        __syncthreads();
        int base = blockIdx.x * CHUNK;
        int cnt = min(CHUNK, NE - base);
        for (int i = t; i < cnt; i += 256) {
            int s = src[base + i];
            int d = dst[base + i];
            int b = d >> 9;
            smem.a.pay[i] = ((unsigned)(d & 511) << 17) | (unsigned)s;
            smem.a.buc[i] = (unsigned char)b;
            atomicAdd(&smem.a.h[b], 1);
        }
        __syncthreads();
        for (int i = t; i < NBUC; i += 256)
            smem.a.lcur[i] = smem.a.h[i] ? atomicAdd(&gcur[i], smem.a.h[i]) : 0;
        __syncthreads();
        for (int i = t; i < cnt; i += 256) {
            int p = atomicAdd(&smem.a.lcur[smem.a.buc[i]], 1);
            ebuf[p] = smem.a.pay[i];
        }
    } else {
        // ---------------- proj1: MFMA bf16 ----------------
        int n0 = (blockIdx.x - NCHUNK) * 128;
        // stage x-tile -> bf16 LDS, swizzled windows
#pragma unroll
        for (int u = 0; u < 8; ++u) {
            int fid = u * 256 + t;
            int row = fid >> 4;      // 0..127
            int win = fid & 15;      // 16B window (8 bf16)
            int n = n0 + row;
            uint4 w = make_uint4(0u, 0u, 0u, 0u);
            if (n < NN) {
                const float4* xp = (const float4*)&x[(size_t)n * 128 + win * 8];
                float4 v0 = xp[0], v1 = xp[1];
                w.x = f2bf(v0.x) | (f2bf(v0.y) << 16);
                w.y = f2bf(v0.z) | (f2bf(v0.w) << 16);
                w.z = f2bf(v1.x) | (f2bf(v1.y) << 16);
                w.w = f2bf(v1.z) | (f2bf(v1.w) << 16);
            }
            *(uint4*)((char*)smem.xls + row * 256 + swz(row, win) * 16) = w;
        }
        __syncthreads();
        int wv = t >> 6;          // wave 0..3 -> row-tiles {2wv, 2wv+1}
        int l = t & 63;
        int lr = l & 15;          // A-row / B-col / C-col within tile
        int lg = l >> 4;          // k-group
        f32x4 acc[2][8];
#pragma unroll
        for (int rt = 0; rt < 2; ++rt)
#pragma unroll
            for (int ct = 0; ct < 8; ++ct) acc[rt][ct] = (f32x4)0.f;
        bhalf8 afr[2], bfr[8];
        for (int ks = 0; ks < 4; ++ks) {
#pragma unroll
            for (int rt = 0; rt < 2; ++rt) {
                int row = (wv * 2 + rt) * 16 + lr;
                int win = ks * 4 + lg;
                afr[rt] = *(bhalf8*)((char*)smem.xls + row * 256 + swz(row, win) * 16);
            }
#pragma unroll
            for (int ct = 0; ct < 8; ++ct)
                bfr[ct] = *(const bhalf8*)&wb[(ct * 16 + lr) * 128 + ks * 32 + lg * 8];
#pragma unroll
            for (int ct = 0; ct < 8; ++ct) {
                acc[0][ct] = __builtin_amdgcn_mfma_f32_16x16x32_bf16(
                    afr[0], bfr[ct], acc[0][ct], 0, 0, 0);
                acc[1][ct] = __builtin_amdgcn_mfma_f32_16x16x32_bf16(
                    afr[1], bfr[ct], acc[1][ct], 0, 0, 0);
            }
        }
        // C write: row = lg*4+j, col = lr
        unsigned short* p1h = (unsigned short*)p1b;
#pragma unroll
        for (int rt = 0; rt < 2; ++rt) {
#pragma unroll
            for (int j = 0; j < 4; ++j) {
                int n = n0 + (wv * 2 + rt) * 16 + lg * 4 + j;
                if (n < NN) {
#pragma unroll
                    for (int ct = 0; ct < 8; ++ct) {
                        float vv = acc[rt][ct][j];
                        int ch = ct * 16 + lr;
                        if (ct < 4)
                            p1h[(size_t)n * 64 + ch] = (unsigned short)f2bf(vv);
                        else
                            r1[(size_t)n * 64 + (ch - 64)] = vv;
                    }
                }
            }
        }
    }
}

// ---- pass B: per bucket -> per-node counts/offsets (coalesced), skey ------
__global__ __launch_bounds__(512) void k_passB(const unsigned int* __restrict__ ebuf,
                                               const int* __restrict__ gcur,
                                               int* __restrict__ offs,
                                               int* __restrict__ cnti,
                                               int* __restrict__ skey) {
    __shared__ int lcnt[BW];
    __shared__ int lcur[BW];
    __shared__ int s2[256];
    int b = blockIdx.x, t = threadIdx.x;
    int beg = b * CAP, end = gcur[b];
    lcnt[t] = 0;
    __syncthreads();
    for (int i = beg + t; i < end; i += 512)
        atomicAdd(&lcnt[ebuf[i] >> 17], 1);
    __syncthreads();
    int c0 = 0, c1 = 0;
    if (t < 256) {
        c0 = lcnt[2 * t];
        c1 = lcnt[2 * t + 1];
        s2[t] = c0 + c1;
    }
    __syncthreads();
    for (int d = 1; d < 256; d <<= 1) {
        int a = 0;
        if (t < 256 && t >= d) a = s2[t - d];
        __syncthreads();
        if (t < 256) s2[t] += a;
        __syncthreads();
    }
    if (t < 256) {
        int excl = s2[t] - (c0 + c1);
        int o0 = beg + excl;
        int o1 = o0 + c0;
        lcur[2 * t] = o0;
        lcur[2 * t + 1] = o1;
        int n0 = b * BW + 2 * t;
        if (n0 < NN)     { offs[n0] = o0;     cnti[n0] = c0; }
        if (n0 + 1 < NN) { offs[n0 + 1] = o1; cnti[n0 + 1] = c1; }
    }
    __syncthreads();
    for (int i = beg + t; i < end; i += 512) {
        unsigned v = ebuf[i];
        int p = atomicAdd(&lcur[v >> 17], 1);
        skey[p] = (int)(v & 0x1FFFFu);
    }
}

// ---- agg1 + combine1: wave per node -> h (f32, in place over r1) ----
// 8 independent p1b loads in flight per lane.
__global__ __launch_bounds__(256) void k_agg1(const unsigned int* __restrict__ p1b,
                                              float* __restrict__ r1,
                                              const int* __restrict__ skey,
                                              const int* __restrict__ offs,
                                              const int* __restrict__ cnti,
                                              const float* __restrict__ b1) {
    int n = (blockIdx.x * 256 + threadIdx.x) >> 6;
    int l = threadIdx.x & 63;
    if (n >= NN) return;
    int half = l >> 5;      // 0: even edges, 1: odd edges
    int i32 = l & 31;       // channel-pair index
    int off = offs[n];
    int dc = cnti[n];
    float a0 = 0.f, a1 = 0.f;
    int e = half;
    for (; e + 14 < dc; e += 16) {
        int s0 = skey[off + e];
        int s1 = skey[off + e + 2];
        int s2 = skey[off + e + 4];
        int s3 = skey[off + e + 6];
        int s4 = skey[off + e + 8];
        int s5 = skey[off + e + 10];
        int s6 = skey[off + e + 12];
        int s7 = skey[off + e + 14];
        unsigned v0 = p1b[(size_t)s0 * 32 + i32];
        unsigned v1 = p1b[(size_t)s1 * 32 + i32];
        unsigned v2 = p1b[(size_t)s2 * 32 + i32];
        unsigned v3 = p1b[(size_t)s3 * 32 + i32];
        unsigned v4 = p1b[(size_t)s4 * 32 + i32];
        unsigned v5 = p1b[(size_t)s5 * 32 + i32];
        unsigned v6 = p1b[(size_t)s6 * 32 + i32];
        unsigned v7 = p1b[(size_t)s7 * 32 + i32];
        a0 += bf_lo(v0); a1 += bf_hi(v0);
        a0 += bf_lo(v1); a1 += bf_hi(v1);
        a0 += bf_lo(v2); a1 += bf_hi(v2);
        a0 += bf_lo(v3); a1 += bf_hi(v3);
        a0 += bf_lo(v4); a1 += bf_hi(v4);
        a0 += bf_lo(v5); a1 += bf_hi(v5);
        a0 += bf_lo(v6); a1 += bf_hi(v6);
        a0 += bf_lo(v7); a1 += bf_hi(v7);
    }
    for (; e + 6 < dc; e += 8) {
        int s0 = skey[off + e];
        int s1 = skey[off + e + 2];
        int s2 = skey[off + e + 4];
        int s3 = skey[off + e + 6];
        unsigned v0 = p1b[(size_t)s0 * 32 + i32];
        unsigned v1 = p1b[(size_t)s1 * 32 + i32];
        unsigned v2 = p1b[(size_t)s2 * 32 + i32];
        unsigned v3 = p1b[(size_t)s3 * 32 + i32];
        a0 += bf_lo(v0); a1 += bf_hi(v0);
        a0 += bf_lo(v1); a1 += bf_hi(v1);
        a0 += bf_lo(v2); a1 += bf_hi(v2);
        a0 += bf_lo(v3); a1 += bf_hi(v3);
    }
    for (; e < dc; e += 2) {
        int s0 = skey[off + e];
        unsigned v0 = p1b[(size_t)s0 * 32 + i32];
        a0 += bf_lo(v0); a1 += bf_hi(v0);
    }
    a0 += __shfl_xor(a0, 32);
    a1 += __shfl_xor(a1, 32);
    float ca = __shfl(a0, l >> 1);
    float cb = __shfl(a1, l >> 1);
    float acc = (l & 1) ? cb : ca;

    float inv = (dc > 0) ? 1.f / (float)dc : 0.f;
    float h = fmaxf(acc * inv + r1[(size_t)n * 64 + l] + b1[l], 0.f);
    r1[(size_t)n * 64 + l] = h;   // h overwrites r1 (row owned by this wave)
}

// ---- proj2: dense, thread per node; p2 stride 8 (32B-aligned rows) --------
__global__ __launch_bounds__(256) void k_proj2(const float* __restrict__ h,
                                               const float* __restrict__ W2l,
                                               const float* __restrict__ W2r,
                                               float* __restrict__ p2,
                                               float* __restrict__ r2) {
    __shared__ float swl[NC][64];
    __shared__ float swr[NC][64];
    int t = threadIdx.x;
    for (int i = t; i < NC * 64; i += 256) {
        swl[i >> 6][i & 63] = W2l[i];
        swr[i >> 6][i & 63] = W2r[i];
    }
    __syncthreads();
    int n = blockIdx.x * 256 + t;
    if (n >= NN) return;
    float al[NC], ar[NC];
#pragma unroll
    for (int c = 0; c < NC; ++c) { al[c] = 0.f; ar[c] = 0.f; }
    const float4* H = (const float4*)(h + (size_t)n * 64);
#pragma unroll
    for (int q = 0; q < 16; ++q) {
        float4 u = H[q];
        int k = q * 4;
#pragma unroll
        for (int c = 0; c < NC; ++c) {
            al[c] += u.x * swl[c][k] + u.y * swl[c][k + 1] +
                     u.z * swl[c][k + 2] + u.w * swl[c][k + 3];
            ar[c] += u.x * swr[c][k] + u.y * swr[c][k + 1] +
                     u.z * swr[c][k + 2] + u.w * swr[c][k + 3];
        }
    }
#pragma unroll
    for (int c = 0; c < NC; ++c) {
        p2[(size_t)n * 8 + c] = al[c];      // stride 8
        r2[(size_t)n * NC + c] = ar[c];
    }
}

// ---- agg2 + bias + log_softmax fused: 8 lanes per node; 8-deep gather ILP -
__global__ __launch_bounds__(256) void k_agg2f(const float* __restrict__ p2,
                                               const float* __restrict__ r2,
                                               const int* __restrict__ skey,
                                               const int* __restrict__ offs,
                                               const int* __restrict__ cnti,
                                               const float* __restrict__ b2,
                                               float* __restrict__ out) {
    int tid = blockIdx.x * 256 + threadIdx.x;
    int n = tid >> 3;
    int c = tid & 7;
    if (n >= NN) return;
    bool act = (c < NC);
    int off = offs[n];
    int dc = cnti[n];
    int i = off, end = off + dc;
    float acc = 0.f;
    for (; i + 7 < end; i += 8) {
        int s0 = skey[i],     s1 = skey[i + 1], s2 = skey[i + 2], s3 = skey[i + 3];
        int s4 = skey[i + 4], s5 = skey[i + 5], s6 = skey[i + 6], s7 = skey[i + 7];
        if (act) {
            float x0 = p2[(size_t)s0 * 8 + c];
            float x1 = p2[(size_t)s1 * 8 + c];
            float x2 = p2[(size_t)s2 * 8 + c];
            float x3 = p2[(size_t)s3 * 8 + c];
            float x4 = p2[(size_t)s4 * 8 + c];
            float x5 = p2[(size_t)s5 * 8 + c];
            float x6 = p2[(size_t)s6 * 8 + c];
            float x7 = p2[(size_t)s7 * 8 + c];
            acc += x0 + x1 + x2 + x3 + x4 + x5 + x6 + x7;
        }
    }
    for (; i + 3 < end; i += 4) {
        int s0 = skey[i], s1 = skey[i + 1], s2 = skey[i + 2], s3 = skey[i + 3];
        if (act) {
            acc += p2[(size_t)s0 * 8 + c];
            acc += p2[(size_t)s1 * 8 + c];
            acc += p2[(size_t)s2 * 8 + c];
            acc += p2[(size_t)s3 * 8 + c];
        }
    }
    for (; i < end; ++i) if (act) acc += p2[(size_t)skey[i] * 8 + c];
    float inv = (dc > 0) ? 1.f / (float)dc : 0.f;
    float v = act ? (acc * inv + r2[(size_t)n * NC + c] + b2[c]) : -INFINITY;
    float m = v;
#pragma unroll
    for (int d = 1; d < 8; d <<= 1) m = fmaxf(m, __shfl_xor(m, d));
    float ev = act ? expf(v - m) : 0.f;
    float s = ev;
#pragma unroll
    for (int d = 1; d < 8; d <<= 1) s += __shfl_xor(s, d);
    if (act) out[(size_t)n * NC + c] = v - m - logf(s);
}

extern "C" void kernel_launch(void* const* d_in, const int* in_sizes, int n_in,
                              void* d_out, int out_size, void* d_ws, size_t ws_size,
                              hipStream_t stream) {
    const float* x   = (const float*)d_in[0];
    const int*   ei  = (const int*)d_in[1];   // [2, NE] int32
    const float* W1l = (const float*)d_in[2];
    const float* W1r = (const float*)d_in[3];
    const float* b1  = (const float*)d_in[4];
    const float* W2l = (const float*)d_in[5];
    const float* W2r = (const float*)d_in[6];
    const float* b2  = (const float*)d_in[7];
    float* out = (float*)d_out;

    const int* src = ei;
    const int* dst = ei + NE;

    // workspace layout (4-byte units), ~78 MB total
    int* gcur  = (int*)d_ws;                // 256
    int* cnti  = gcur + 256;                // NN
    int* offs  = cnti + NN;                 // NN
    unsigned int* ebuf = (unsigned int*)(offs + NN);        // NBUC*CAP
    int* skey  = (int*)(ebuf + (size_t)NBUC * CAP);         // NBUC*CAP
    unsigned short* wb = (unsigned short*)(skey + (size_t)NBUC * CAP); // 16384 bf16
    unsigned int* p1b = (unsigned int*)((int*)wb + 8192);   // NN*32
    float* r1  = (float*)(p1b + (size_t)NN * 32);           // NN*64; becomes h
    float* p2  = r1 + (size_t)NN * HID;     // NN*8 (stride 8)
    float* r2  = p2 + (size_t)NN * 8;       // NN*7

    k_init   <<<17, 256, 0, stream>>>(gcur, W1l, W1r, wb);
    k_pa_proj<<<NCHUNK + PROJB, 256, 0, stream>>>(src, dst, gcur, ebuf,
                                                  x, wb, p1b, r1);
    k_passB  <<<NBUC, 512, 0, stream>>>(ebuf, gcur, offs, cnti, skey);
    k_agg1   <<<(NN * 64 + 255) / 256, 256, 0, stream>>>(p1b, r1, skey, offs,
                                                         cnti, b1);
    k_proj2  <<<(NN + 255) / 256, 256, 0, stream>>>(r1, W2l, W2r, p2, r2);
    k_agg2f  <<<(NN * 8 + 255) / 256, 256, 0, stream>>>(p2, r2, skey, offs,
                                                        cnti, b2, out);
}